// Round 6
// baseline (110.017 us; speedup 1.0000x reference)
//
#include <hip/hip_runtime.h>

namespace {
constexpr int CIN = 64, COUT = 64, SS = 1024, KK = 3;
constexpr int STL = 4;            // s per block
constexpr int POS = STL + 2;      // 6 halo positions
constexpr int NCG = 4, CPG = 16;  // 4 waves, 16 channels each
constexpr int BB  = 8;            // batches per block (b-split: 2 blocks cover b=16)
}

// R6: 2 resident blocks/CU for phase overlap. Block = 256 threads = 4 waves;
// grid = 512 (256 s-tiles x 2 b-halves) = 2 blocks/CU. Per-CU work (FMA count,
// LDS reads, weight bytes) identical to R5; blocks desync so one block's
// staging/epilogue barriers overlap the other's BW-bound weight c-loop.
// acc[4][8]=32 regs + 3-deep rotating weight prefetch (36 regs) -> live ~100,
// fits the immovable 128-VGPR cap (R1-R3 evidence) with margin.
// Epilogue: ONE barrier round (was 4): partial buffer 4cg x 2048 = 32 KB exactly;
// XOR bank-swizzle (e ^ (((e>>5)&7)<<2)) makes write side 2-way (free) and keeps
// read side conflict-free.
// Weight sharing: b-half twins (p, p+256) have equal bid%8 -> same XCD under
// round-robin dispatch; all 512 blocks co-resident -> twin's weight lines L2-hit,
// HBM weight fetch stays ~50 MB.
// CRITICAL (kept): every array index is compile-time (fully unrolled) -- runtime
// indexing demotes arrays to scratch.
__global__ __launch_bounds__(256)
void locon1d(const float* __restrict__ in, const float* __restrict__ wt,
             const float* __restrict__ bias, float* __restrict__ out) {
  __shared__ float smem[8192];  // 32 KB: stage uses 3072 floats; partial uses all 8192

  const int tid = threadIdx.x;
  const int sl  = tid & 3;
  const int og  = (tid >> 2) & 15;
  const int cg  = tid >> 6;           // wave id 0..3
  const int bid = blockIdx.x;
  const int p   = bid & 255;          // s-tile id
  const int h   = bid >> 8;           // b-half 0..1
  // XCD swizzle: adjacent s-tiles are p,p+8 -> same XCD -> weight lines merge in L2
  const int st  = ((p & 7) << 5) + (p >> 3);
  const int s0  = st * STL;
  const int s   = s0 + sl;
  const int o0  = og * 4;
  const int cb  = cg * CPG;
  const int b0  = h * BB;

  // ---- weight prologue hoisted above staging: latency hides under the stage ----
  const float* wbase = wt + ((size_t)o0 * CIN + cb) * (SS * KK) + (size_t)s * KK;

  float wA[4][3], wB[4][3], wC[4][3];

  #define WLD(DST, C_) do {                                                    \
    _Pragma("unroll")                                                          \
    for (int oo = 0; oo < 4; ++oo)                                             \
      _Pragma("unroll")                                                        \
      for (int k = 0; k < KK; ++k)                                             \
        DST[oo][k] = wbase[(size_t)oo * (CIN * SS * KK) +                      \
                           (size_t)(C_) * (SS * KK) + k];                      \
  } while (0)

  WLD(wA, 0); WLD(wB, 1); WLD(wC, 2);   // 3 channels in flight before staging

  // ---- stage input tile to LDS: xs[c][p6][b8], 64c x 6pos x 8b = 12 KB ----
  #pragma unroll
  for (int i = 0; i < 3; ++i) {
    const int t  = tid + i * 256;        // 0..767 = 64c * 6p * 2bq
    const int c  = t / 12;
    const int r  = t - c * 12;
    const int bq = r / 6;                // 0..1 (4 b's each)
    const int pp = r - bq * 6;
    const int sg = s0 - 1 + pp;
    const bool v = (unsigned)sg < (unsigned)SS;
    const float* ip = in + ((size_t)(b0 + 4 * bq) * CIN + c) * SS + sg;
    float4 x4;
    x4.x = v ? ip[0] : 0.f;
    x4.y = v ? ip[(size_t)1 * CIN * SS] : 0.f;
    x4.z = v ? ip[(size_t)2 * CIN * SS] : 0.f;
    x4.w = v ? ip[(size_t)3 * CIN * SS] : 0.f;
    *reinterpret_cast<float4*>(&smem[(c * POS + pp) * 8 + 4 * bq]) = x4;
  }
  __syncthreads();

  float acc[4][BB];
  #pragma unroll
  for (int oo = 0; oo < 4; ++oo)
    #pragma unroll
    for (int b = 0; b < BB; ++b) acc[oo][b] = 0.f;

  // compute channel cb+C_ against LDS input tile (weights from register set W)
  #define CMP(W, C_) do {                                                      \
    _Pragma("unroll")                                                          \
    for (int k = 0; k < KK; ++k) {                                             \
      const float* base_ = &smem[((cb + (C_)) * POS + sl + k) * 8];            \
      _Pragma("unroll")                                                        \
      for (int g = 0; g < 2; ++g) {                                            \
        const float4 x4 = *reinterpret_cast<const float4*>(base_ + 4 * g);     \
        _Pragma("unroll")                                                      \
        for (int oo = 0; oo < 4; ++oo) {                                       \
          const float wv = W[oo][k];                                           \
          acc[oo][4 * g + 0] += wv * x4.x;                                     \
          acc[oo][4 * g + 1] += wv * x4.y;                                     \
          acc[oo][4 * g + 2] += wv * x4.z;                                     \
          acc[oo][4 * g + 3] += wv * x4.w;                                     \
        }                                                                      \
      }                                                                        \
    }                                                                          \
  } while (0)

  // 16 c-steps, 3-deep rotation: load c+3 while computing c
  CMP(wA,  0); WLD(wA,  3);
  CMP(wB,  1); WLD(wB,  4);
  CMP(wC,  2); WLD(wC,  5);
  CMP(wA,  3); WLD(wA,  6);
  CMP(wB,  4); WLD(wB,  7);
  CMP(wC,  5); WLD(wC,  8);
  CMP(wA,  6); WLD(wA,  9);
  CMP(wB,  7); WLD(wB, 10);
  CMP(wC,  8); WLD(wC, 11);
  CMP(wA,  9); WLD(wA, 12);
  CMP(wB, 10); WLD(wB, 13);
  CMP(wC, 11); WLD(wC, 14);
  CMP(wA, 12); WLD(wA, 15);
  CMP(wB, 13);
  CMP(wC, 14);
  CMP(wA, 15);

  #undef WLD
  #undef CMP

  // ---- in-block reduction over cg (4 partials), SINGLE round ----
  // e = bb*256 + og*16 + oo*4 + sl  (== output item id within block)
  // swz(e) = e ^ (((e>>5)&7)<<2): write side 2-way banked (free), read side
  // stays conflict-free (XOR key constant within each 32-dword stripe).
  __syncthreads();                      // guards xs-region reuse
  #pragma unroll
  for (int oo = 0; oo < 4; ++oo)
    #pragma unroll
    for (int bb = 0; bb < BB; ++bb) {
      const int e = bb * 256 + (og * 4 + oo) * 4 + sl;
      smem[cg * 2048 + (e ^ (((e >> 5) & 7) << 2))] = acc[oo][bb];
    }
  __syncthreads();
  #pragma unroll
  for (int i = 0; i < 8; ++i) {
    const int item = tid + i * 256;     // (bl 0..7, o 0..63, sl2 0..3)
    const int sw   = item ^ (((item >> 5) & 7) << 2);
    float sum = 0.f;
    #pragma unroll
    for (int g = 0; g < NCG; ++g) sum += smem[g * 2048 + sw];
    const int bl  = item >> 8;
    const int rem = item & 255;
    const int o   = rem >> 2;
    const int s2  = s0 + (rem & 3);
    out[((size_t)(b0 + bl) * COUT + o) * SS + s2] = sum + bias[o * SS + s2];
  }
}

extern "C" void kernel_launch(void* const* d_in, const int* in_sizes, int n_in,
                              void* d_out, int out_size, void* d_ws, size_t ws_size,
                              hipStream_t stream) {
  const float* in = (const float*)d_in[0];
  const float* wt = (const float*)d_in[1];
  const float* bs = (const float*)d_in[2];
  float* out = (float*)d_out;
  // 256 s-tiles x 2 b-halves = 512 blocks x 4 waves = 2 blocks/CU
  hipLaunchKernelGGL(locon1d, dim3(512), dim3(256), 0, stream, in, wt, bs, out);
}

// Round 8
// 94.168 us; speedup vs baseline: 1.1683x; 1.1683x over previous
//
#include <hip/hip_runtime.h>

namespace {
constexpr int CIN = 64, COUT = 64, SS = 1024, KK = 3;
constexpr int STL = 4;            // s per block
constexpr int POS = STL + 2;      // 6 halo positions
constexpr int NCG = 8, CPG = 8;   // 8 c-groups of 8 channels (one wave each)
constexpr int XS_DW   = CIN * POS * 16;          // 6144 dwords input tile
constexpr int PART_DW = NCG * 4096;              // 32768 dwords partials (128 KB)
constexpr int SMEMDW  = XS_DW + PART_DW;         // 38912 dwords = 152 KB (<160 KB/CU; >64KB OK per R1)
}

// R7/R8 = R5 core + barrier elimination. Grid 256 (1 block/CU), 512 thr = 8 waves,
// weights read exactly ONCE (R6 lesson: b-split doubled weight HBM, +10 us).
//
// Changes vs R5:
//  1. Wave-private staging: wave cg only FMAs channels cb..cb+7, so it stages
//     exactly those -> NO barrier between staging and compute; waves desync and
//     keep HBM busy through each other's stage/epilogue phases.
//  2. Weight prologue (3 WLDs) issued BEFORE staging loads: vmcnt is FIFO, so
//     weights complete before the staging x4s the ds_writes wait on.
//  3. Single-round epilogue: 128 KB partial buffer disjoint from staging region;
//     per-wave regions disjoint -> ONE __syncthreads() in the whole kernel
//     (R5 had 9). Swizzle A^=((A>>5)&7)<<2: write side 2-way (free), read side
//     conflict-free. Bias prefetched to regs before the barrier.
//
// CRITICAL (kept): all array indices compile-time (full unroll); live set
// ~110 VGPRs under the immovable 128 cap (R1-R3: allocator ignores
// launch_bounds/waves_per_eu; >128 live => acc spills, 106 MB scratch traffic).
__global__ __launch_bounds__(512)
void locon1d(const float* __restrict__ in, const float* __restrict__ wt,
             const float* __restrict__ bias, float* __restrict__ out) {
  __shared__ float smem[SMEMDW];

  const int tid  = threadIdx.x;
  const int sl   = tid & 3;
  const int og   = (tid >> 2) & 15;
  const int cg   = tid >> 6;          // wave id
  const int lane = tid & 63;
  const int bid  = blockIdx.x;
  // XCD swizzle: adjacent s-tiles are bid,bid+8 -> same XCD -> weight lines merge in L2
  const int st  = ((bid & 7) << 5) + (bid >> 3);
  const int s0  = st * STL;
  const int s   = s0 + sl;
  const int o0  = og * 4;
  const int cb  = cg * CPG;

  // ---- weight prologue FIRST (latency hides under staging; vmcnt FIFO) ----
  const float* wbase = wt + ((size_t)o0 * CIN + cb) * (SS * KK) + (size_t)s * KK;

  float wA[4][3], wB[4][3], wC[4][3];

  #define WLD(DST, C_) do {                                                    \
    _Pragma("unroll")                                                          \
    for (int oo = 0; oo < 4; ++oo)                                             \
      _Pragma("unroll")                                                        \
      for (int k = 0; k < KK; ++k)                                             \
        DST[oo][k] = wbase[(size_t)oo * (CIN * SS * KK) +                      \
                           (size_t)(C_) * (SS * KK) + k];                      \
  } while (0)

  WLD(wA, 0); WLD(wB, 1); WLD(wC, 2);

  // ---- wave-private staging: own 8 channels only, 192 float4 = 3/lane ----
  // xs[c][p][b]: 64c x 6pos x 16b; wave cg covers c = cb..cb+7. No barrier after.
  #pragma unroll
  for (int i = 0; i < 3; ++i) {
    const int t  = lane + i * 64;        // 0..191 = 8c * 6p * 4bq
    const int cl = t / 24;
    const int r  = t - cl * 24;
    const int bq = r / 6;
    const int p  = r - bq * 6;
    const int c  = cb + cl;
    const int sg = s0 - 1 + p;
    const bool v = (unsigned)sg < (unsigned)SS;
    const float* ip = in + ((size_t)(4 * bq) * CIN + c) * SS + sg;
    float4 x4;
    x4.x = v ? ip[0] : 0.f;
    x4.y = v ? ip[(size_t)1 * CIN * SS] : 0.f;
    x4.z = v ? ip[(size_t)2 * CIN * SS] : 0.f;
    x4.w = v ? ip[(size_t)3 * CIN * SS] : 0.f;
    *reinterpret_cast<float4*>(&smem[(c * POS + p) * 16 + 4 * bq]) = x4;
  }
  // same-wave ds_write -> ds_read ordering is guaranteed (in-order LDS per wave)

  float acc[4][16];
  #pragma unroll
  for (int oo = 0; oo < 4; ++oo)
    #pragma unroll
    for (int b = 0; b < 16; ++b) acc[oo][b] = 0.f;

  // compute channel cb+C_ against LDS input tile (weights from register set W)
  #define CMP(W, C_) do {                                                      \
    _Pragma("unroll")                                                          \
    for (int k = 0; k < KK; ++k) {                                             \
      const float* base_ = &smem[((cb + (C_)) * POS + sl + k) * 16];           \
      _Pragma("unroll")                                                        \
      for (int g = 0; g < 4; ++g) {                                            \
        const float4 x4 = *reinterpret_cast<const float4*>(base_ + 4 * g);     \
        _Pragma("unroll")                                                      \
        for (int oo = 0; oo < 4; ++oo) {                                       \
          const float wv = W[oo][k];                                           \
          acc[oo][4 * g + 0] += wv * x4.x;                                     \
          acc[oo][4 * g + 1] += wv * x4.y;                                     \
          acc[oo][4 * g + 2] += wv * x4.z;                                     \
          acc[oo][4 * g + 3] += wv * x4.w;                                     \
        }                                                                      \
      }                                                                        \
    }                                                                          \
  } while (0)

  // 8 c-steps, 3-deep rotation: load c+3 while computing c
  CMP(wA, 0); WLD(wA, 3);
  CMP(wB, 1); WLD(wB, 4);
  CMP(wC, 2); WLD(wC, 5);
  CMP(wA, 3); WLD(wA, 6);
  CMP(wB, 4); WLD(wB, 7);
  CMP(wC, 5);
  CMP(wA, 6);
  CMP(wB, 7);

  #undef WLD
  #undef CMP

  // ---- bias prefetch (issued before the barrier; used after) ----
  float bz[8];
  #pragma unroll
  for (int i = 0; i < 8; ++i) {
    const int item = tid + i * 512;      // (b 0..15, o 0..63, sl2 0..3)
    const int o    = (item >> 2) & 63;
    const int s2   = s0 + (item & 3);
    bz[i] = bias[o * SS + s2];
  }

  // ---- single-round epilogue: partials at smem[XS_DW + cg*4096 + swz(A)] ----
  // A = b*256 + o*4 + sl (o = og*4+oo); swz: A ^ ((A>>5)&7)<<2
  //  write (per wave, fixed oo,b; og,sl vary): 2-way banked -> free (m136)
  //  read  (consecutive items per lane): conflict-free
  // Wave regions disjoint & disjoint from staging -> no barrier before writes.
  #pragma unroll
  for (int oo = 0; oo < 4; ++oo)
    #pragma unroll
    for (int b = 0; b < 16; ++b) {
      const int A = b * 256 + (og * 4 + oo) * 4 + sl;
      smem[XS_DW + cg * 4096 + (A ^ (((A >> 5) & 7) << 2))] = acc[oo][b];
    }
  __syncthreads();                       // the kernel's ONLY barrier
  #pragma unroll
  for (int i = 0; i < 8; ++i) {
    const int item = tid + i * 512;
    const int sw   = item ^ (((item >> 5) & 7) << 2);
    float sum = 0.f;
    #pragma unroll
    for (int g = 0; g < NCG; ++g) sum += smem[XS_DW + g * 4096 + sw];
    const int b   = item >> 8;
    const int o   = (item >> 2) & 63;
    const int s2  = s0 + (item & 3);
    out[((size_t)b * COUT + o) * SS + s2] = sum + bz[i];
  }
}

extern "C" void kernel_launch(void* const* d_in, const int* in_sizes, int n_in,
                              void* d_out, int out_size, void* d_ws, size_t ws_size,
                              hipStream_t stream) {
  const float* in = (const float*)d_in[0];
  const float* wt = (const float*)d_in[1];
  const float* bs = (const float*)d_in[2];
  float* out = (float*)d_out;
  // 256 s-tiles (4 s each), full o & c per block; 256 blocks x 8 waves, 1/CU
  hipLaunchKernelGGL(locon1d, dim3(256), dim3(512), 0, stream, in, wt, bs, out);
}